// Round 3
// baseline (893.287 us; speedup 1.0000x reference)
//
#include <hip/hip_runtime.h>
#include <hip/hip_bf16.h>
#include <math.h>

// Problem constants (fixed by setup_inputs: seed 0, shapes below)
#define N_NODES 8192
#define F_IN    512
#define HID     128
#define NCLS    16
#define MAX_ELL 256   // avg degree ~65, sigma ~8; 256 is unreachable
#define C_RES   0.5555555555555556f   // 1/(1+alpha), alpha=0.8
#define C_PROP  0.4444444444444445f   // alpha/(1+alpha)

// Load input element i as float, from either bf16 or fp32 storage.
__device__ __forceinline__ float ld_in(const void* p, size_t i, bool bf) {
    return bf ? __bfloat162float(((const __hip_bfloat16*)p)[i])
              : ((const float*)p)[i];
}

// ---------------------------------------------------------------------------
// Kernel 0: detect input dtype from adjacency bit patterns.
// fp32 0/1 data: every 32-bit word is 0x00000000 or 0x3F800000 (low half
// never 0x3F80). bf16 0/1 data: a 1.0 at an even element index puts 0x3F80
// in the LOW half of a word (~260 expected in the first 64K words).
// flag = 1 -> bf16 storage, 0 -> fp32 storage.
// ---------------------------------------------------------------------------
__global__ void detect_dtype_kernel(const unsigned int* __restrict__ adjw,
                                    int* __restrict__ flag)
{
    __shared__ int found;
    if (threadIdx.x == 0) found = 0;
    __syncthreads();
    int local = 0;
    for (int i = threadIdx.x; i < 65536; i += blockDim.x)
        if ((adjw[i] & 0xFFFFu) == 0x3F80u) local = 1;
    if (local) atomicOr(&found, 1);
    __syncthreads();
    if (threadIdx.x == 0) *flag = found;
}

// ---------------------------------------------------------------------------
// Kernel 1: scan dense adjacency row -> ELL column list + degree + dinv.
// One block per row; uint4 loads, fully coalesced, dual dtype paths.
// deg = (#nonzeros in row) + 1 (the +I self-loop).
// ---------------------------------------------------------------------------
__global__ void build_ell_kernel(const void* __restrict__ adj_,
                                 int* __restrict__ ell,
                                 int* __restrict__ nnz,
                                 float* __restrict__ dinv,
                                 const int* __restrict__ flag)
{
    const int r = blockIdx.x;
    const bool bf = (*flag != 0);
    __shared__ int cnt;
    if (threadIdx.x == 0) cnt = 0;
    __syncthreads();

    int* __restrict__ erow = ell + (size_t)r * MAX_ELL;

    if (bf) {
        const uint4* row4 = reinterpret_cast<const uint4*>(
            (const __hip_bfloat16*)adj_ + (size_t)r * N_NODES);
        for (int b = threadIdx.x; b < N_NODES / 8; b += blockDim.x) {
            const uint4 v = row4[b];
            const int base = b * 8;
            const unsigned int w[4] = {v.x, v.y, v.z, v.w};
            #pragma unroll
            for (int q = 0; q < 4; ++q) {
                if (w[q] & 0xFFFFu) {             // low bf16 element
                    int p = atomicAdd(&cnt, 1);
                    if (p < MAX_ELL) erow[p] = base + q * 2;
                }
                if (w[q] >> 16) {                 // high bf16 element
                    int p = atomicAdd(&cnt, 1);
                    if (p < MAX_ELL) erow[p] = base + q * 2 + 1;
                }
            }
        }
    } else {
        const uint4* row4 = reinterpret_cast<const uint4*>(
            (const float*)adj_ + (size_t)r * N_NODES);
        for (int b = threadIdx.x; b < N_NODES / 4; b += blockDim.x) {
            const uint4 v = row4[b];
            const int base = b * 4;
            const unsigned int w[4] = {v.x, v.y, v.z, v.w};
            #pragma unroll
            for (int q = 0; q < 4; ++q) {
                if (w[q]) {                        // 1.0f != 0 bit pattern
                    int p = atomicAdd(&cnt, 1);
                    if (p < MAX_ELL) erow[p] = base + q;
                }
            }
        }
    }
    __syncthreads();
    if (threadIdx.x == 0) {
        int c = cnt; if (c > MAX_ELL) c = MAX_ELL;
        nnz[r] = c;
        dinv[r] = rsqrtf((float)cnt + 1.0f);  // deg >= 1
    }
}

// ---------------------------------------------------------------------------
// Kernel 2: h1 = x @ W1   (8192x512 @ 512x128 -> fp32)
// 4 rows per 512-thread block; W1[k*128+c] coalesced, x row broadcast.
// ---------------------------------------------------------------------------
template <bool BF>
__device__ __forceinline__ void gemm_xw1_body(const void* __restrict__ x,
                                              const void* __restrict__ W1,
                                              float* __restrict__ h1)
{
    const int c = threadIdx.x & (HID - 1);
    const int r = blockIdx.x * 4 + (threadIdx.x >> 7);
    float acc = 0.f;
    #pragma unroll 8
    for (int k = 0; k < F_IN; ++k)
        acc = fmaf(ld_in(x, (size_t)r * F_IN + k, BF),
                   ld_in(W1, (size_t)k * HID + c, BF), acc);
    h1[(size_t)r * HID + c] = acc;
}

__global__ void gemm_xw1_kernel(const void* __restrict__ x,
                                const void* __restrict__ W1,
                                float* __restrict__ h1,
                                const int* __restrict__ flag)
{
    if (*flag) gemm_xw1_body<true>(x, W1, h1);
    else       gemm_xw1_body<false>(x, W1, h1);
}

// ---------------------------------------------------------------------------
// Kernel 3: one diffusion step (fp32 workspace in/out)
//   vout_i = C_PROP * dinv_i * ( sum_j dinv_j*vin_j + dinv_i*vin_i ) + C_RES*h_i
// FINAL_RELU: + b1 then relu epilogue (layer-1 last step).
// ---------------------------------------------------------------------------
template <int F, int RPB, bool FINAL_RELU>
__global__ void diffuse_kernel(const float* __restrict__ vin,
                               const float* __restrict__ h,
                               float* __restrict__ vout,
                               const int* __restrict__ ell,
                               const int* __restrict__ nnz,
                               const float* __restrict__ dinv,
                               const void* __restrict__ bias,
                               const int* __restrict__ flag)
{
    const int local = threadIdx.x;
    const int c = local % F;
    const int r = blockIdx.x * RPB + local / F;
    const float dr = dinv[r];
    const int nn = nnz[r];
    const int* __restrict__ erow = ell + (size_t)r * MAX_ELL;

    float a0 = 0.f, a1 = 0.f, a2 = 0.f, a3 = 0.f;
    int t = 0;
    for (; t + 4 <= nn; t += 4) {
        const int j0 = erow[t + 0];
        const int j1 = erow[t + 1];
        const int j2 = erow[t + 2];
        const int j3 = erow[t + 3];
        a0 += dinv[j0] * vin[(size_t)j0 * F + c];
        a1 += dinv[j1] * vin[(size_t)j1 * F + c];
        a2 += dinv[j2] * vin[(size_t)j2 * F + c];
        a3 += dinv[j3] * vin[(size_t)j3 * F + c];
    }
    for (; t < nn; ++t) {
        const int j = erow[t];
        a0 += dinv[j] * vin[(size_t)j * F + c];
    }
    float acc = (a0 + a1) + (a2 + a3);
    acc += dr * vin[(size_t)r * F + c];        // self-loop (+I) term
    float val = C_PROP * dr * acc + C_RES * h[(size_t)r * F + c];
    if (FINAL_RELU) {
        val += ld_in(bias, c, *flag != 0);
        val = fmaxf(val, 0.f);
    }
    vout[(size_t)r * F + c] = val;
}

// ---------------------------------------------------------------------------
// Kernel 4: h2 = relu_out1 @ W2   (8192x128 @ 128x16, fp32 x in -> fp32)
// ---------------------------------------------------------------------------
__global__ void gemm_hw2_kernel(const float* __restrict__ in,
                                const void* __restrict__ W2,
                                float* __restrict__ h2,
                                const int* __restrict__ flag)
{
    const bool bf = (*flag != 0);
    const int c = threadIdx.x & (NCLS - 1);
    const int r = blockIdx.x * 16 + (threadIdx.x >> 4);
    const float* ir = in + (size_t)r * HID;
    float acc = 0.f;
    #pragma unroll 8
    for (int k = 0; k < HID; ++k)
        acc = fmaf(ir[k], ld_in(W2, (size_t)k * NCLS + c, bf), acc);
    h2[(size_t)r * NCLS + c] = acc;
}

// ---------------------------------------------------------------------------
// Kernel 5: out = log_softmax(in + b2) row-wise. Output dtype matches input
// storage dtype (bf16 iff inputs bf16).
// ---------------------------------------------------------------------------
__global__ void final_lsm_kernel(const float* __restrict__ in,
                                 const void* __restrict__ b2,
                                 void* __restrict__ out,
                                 const int* __restrict__ flag)
{
    const bool bf = (*flag != 0);
    const int r = blockIdx.x * blockDim.x + threadIdx.x;
    if (r >= N_NODES) return;
    float v[NCLS];
    float mx = -1e30f;
    #pragma unroll
    for (int k = 0; k < NCLS; ++k) {
        v[k] = in[(size_t)r * NCLS + k] + ld_in(b2, k, bf);
        mx = fmaxf(mx, v[k]);
    }
    float s = 0.f;
    #pragma unroll
    for (int k = 0; k < NCLS; ++k) s += __expf(v[k] - mx);
    const float lse = mx + __logf(s);
    #pragma unroll
    for (int k = 0; k < NCLS; ++k) {
        const float o = v[k] - lse;
        if (bf) ((__hip_bfloat16*)out)[(size_t)r * NCLS + k] = __float2bfloat16(o);
        else    ((float*)out)[(size_t)r * NCLS + k] = o;
    }
}

// ---------------------------------------------------------------------------
extern "C" void kernel_launch(void* const* d_in, const int* in_sizes, int n_in,
                              void* d_out, int out_size, void* d_ws, size_t ws_size,
                              hipStream_t stream)
{
    const void* x   = d_in[0];
    const void* adj = d_in[1];
    const void* W1  = d_in[2];
    const void* b1  = d_in[3];
    const void* W2  = d_in[4];
    const void* b2  = d_in[5];

    // Workspace carve-up (~21.7 MB total)
    char* ws = (char*)d_ws;
    size_t off = 0;
    auto carve = [&](size_t bytes) -> void* {
        void* p = ws + off;
        off += (bytes + 255) & ~(size_t)255;
        return p;
    };
    int*   flag = (int*)  carve(256);
    int*   ell  = (int*)  carve((size_t)N_NODES * MAX_ELL * sizeof(int)); // 8 MB
    int*   nnz  = (int*)  carve((size_t)N_NODES * sizeof(int));
    float* dinv = (float*)carve((size_t)N_NODES * sizeof(float));
    float* h1   = (float*)carve((size_t)N_NODES * HID * sizeof(float));  // 4 MB
    float* bufA = (float*)carve((size_t)N_NODES * HID * sizeof(float));  // 4 MB
    float* bufB = (float*)carve((size_t)N_NODES * HID * sizeof(float));  // 4 MB
    float* h2   = (float*)carve((size_t)N_NODES * NCLS * sizeof(float)); // 512 KB
    float* c2A  = (float*)carve((size_t)N_NODES * NCLS * sizeof(float));
    float* c2B  = (float*)carve((size_t)N_NODES * NCLS * sizeof(float));

    // 0) detect storage dtype from adjacency bit patterns
    detect_dtype_kernel<<<1, 1024, 0, stream>>>((const unsigned int*)adj, flag);

    // 1) adjacency -> ELL + dinv
    build_ell_kernel<<<N_NODES, 256, 0, stream>>>(adj, ell, nnz, dinv, flag);

    // 2) h1 = x @ W1
    gemm_xw1_kernel<<<N_NODES / 4, 512, 0, stream>>>(x, W1, h1, flag);

    // 3) layer-1 diffusion: 8 steps, ping-pong; last step fuses +b1, relu
    const float* cur1 = h1;
    {
        float* bufs[2] = {bufA, bufB};
        for (int s = 0; s < 8; ++s) {
            float* dst = bufs[s & 1];
            if (s == 7)
                diffuse_kernel<HID, 2, true><<<N_NODES / 2, 256, 0, stream>>>(
                    cur1, h1, dst, ell, nnz, dinv, b1, flag);
            else
                diffuse_kernel<HID, 2, false><<<N_NODES / 2, 256, 0, stream>>>(
                    cur1, h1, dst, ell, nnz, dinv, b1, flag);
            cur1 = dst;
        }
    }

    // 4) h2 = relu_out1 @ W2
    gemm_hw2_kernel<<<N_NODES / 16, 256, 0, stream>>>(cur1, W2, h2, flag);

    // 5) layer-2 diffusion: 8 steps on 16-wide features
    const float* cur2 = h2;
    {
        float* bufs[2] = {c2A, c2B};
        for (int s = 0; s < 8; ++s) {
            float* dst = bufs[s & 1];
            diffuse_kernel<NCLS, 16, false><<<N_NODES / 16, 256, 0, stream>>>(
                cur2, h2, dst, ell, nnz, dinv, b2, flag);
            cur2 = dst;
        }
    }

    // 6) log_softmax -> out (dtype-matched)
    final_lsm_kernel<<<N_NODES / 256, 256, 0, stream>>>(cur2, b2, d_out, flag);

    (void)in_sizes; (void)n_in; (void)out_size; (void)ws_size;
}

// Round 4
// 765.972 us; speedup vs baseline: 1.1662x; 1.1662x over previous
//
#include <hip/hip_runtime.h>
#include <hip/hip_fp16.h>
#include <math.h>

// Net_76854144794847: GSDN dense-graph diffusion GCN. fp32 in / fp32 out
// (proven round 2/3: bf16 interpretation NaNs; fp32 path passed).
#define N_NODES 8192
#define F_IN    512
#define HID     128
#define NCLS    16
#define MAX_ELL 256   // deg ~ 65 +/- 8; 256 unreachable
#define C_RES   0.5555555555555556f   // 1/(1+alpha), alpha=0.8
#define C_PROP  0.4444444444444445f   // alpha/(1+alpha)

// ---- half4 <-> float4 helpers (8-byte vector ld/st of 4 fp16) --------------
__device__ __forceinline__ float4 ld_h4(const __half* p) {
    const uint2 u = *reinterpret_cast<const uint2*>(p);
    const __half2 h0 = *reinterpret_cast<const __half2*>(&u.x);
    const __half2 h1 = *reinterpret_cast<const __half2*>(&u.y);
    const float2 f0 = __half22float2(h0);
    const float2 f1 = __half22float2(h1);
    return make_float4(f0.x, f0.y, f1.x, f1.y);
}
__device__ __forceinline__ void st_h4(__half* p, float4 v) {
    __half2 h0 = __floats2half2_rn(v.x, v.y);
    __half2 h1 = __floats2half2_rn(v.z, v.w);
    uint2 u;
    u.x = *reinterpret_cast<unsigned int*>(&h0);
    u.y = *reinterpret_cast<unsigned int*>(&h1);
    *reinterpret_cast<uint2*>(p) = u;
}
__device__ __forceinline__ void add4(float4& a, const float4 b) {
    a.x += b.x; a.y += b.y; a.z += b.z; a.w += b.w;
}

// ---------------------------------------------------------------------------
// 1) dense fp32 adjacency -> ELL + dinv + A_r (= cprop*dinv^2). One block/row.
//    deg = rowsum(A) + 1 (self-loop). 268 MB read: the HBM floor (~45us).
// ---------------------------------------------------------------------------
__global__ void build_ell_kernel(const float* __restrict__ adj,
                                 int* __restrict__ ell,
                                 int* __restrict__ nnz,
                                 float* __restrict__ dinv,
                                 float* __restrict__ arow)
{
    const int r = blockIdx.x;
    __shared__ int cnt;
    if (threadIdx.x == 0) cnt = 0;
    __syncthreads();
    const uint4* row4 = reinterpret_cast<const uint4*>(adj + (size_t)r * N_NODES);
    int* __restrict__ erow = ell + (size_t)r * MAX_ELL;
    for (int b = threadIdx.x; b < N_NODES / 4; b += blockDim.x) {
        const uint4 v = row4[b];
        const int base = b * 4;
        if (v.x) { int p = atomicAdd(&cnt, 1); if (p < MAX_ELL) erow[p] = base + 0; }
        if (v.y) { int p = atomicAdd(&cnt, 1); if (p < MAX_ELL) erow[p] = base + 1; }
        if (v.z) { int p = atomicAdd(&cnt, 1); if (p < MAX_ELL) erow[p] = base + 2; }
        if (v.w) { int p = atomicAdd(&cnt, 1); if (p < MAX_ELL) erow[p] = base + 3; }
    }
    __syncthreads();
    if (threadIdx.x == 0) {
        int c = cnt; if (c > MAX_ELL) c = MAX_ELL;
        nnz[r] = c;
        const float di = rsqrtf((float)cnt + 1.0f);
        dinv[r] = di;
        arow[r] = C_PROP * di * di;
    }
}

// ---------------------------------------------------------------------------
// 2) h1 = x @ W1 (fp32 8192x512 @ 512x128), tiled: block = 32 rows x 128 cols,
//    thread = 4 rows x 4 cols. Epilogue writes h1 (fp32), s0 = dinv*h (fp16),
//    hb = cres*dinv*h (fp32).
// ---------------------------------------------------------------------------
__global__ __launch_bounds__(256) void gemm_xw1_kernel(
    const float* __restrict__ x, const float* __restrict__ W1,
    const float* __restrict__ dinv,
    float* __restrict__ h1, __half* __restrict__ s0, float* __restrict__ hb)
{
    const int tx = threadIdx.x & 31;        // col group: cols 4*tx..4*tx+3
    const int ty = threadIdx.x >> 5;        // row group: 4 rows each
    const int c  = tx * 4;
    const int r0 = blockIdx.x * 32 + ty * 4;

    const float4* W4 = reinterpret_cast<const float4*>(W1);
    const float4* xr[4];
    #pragma unroll
    for (int i = 0; i < 4; ++i)
        xr[i] = reinterpret_cast<const float4*>(x + (size_t)(r0 + i) * F_IN);

    float4 acc[4] = {{0,0,0,0},{0,0,0,0},{0,0,0,0},{0,0,0,0}};

    #pragma unroll 2
    for (int kk = 0; kk < F_IN / 4; ++kk) {
        const int k = kk * 4;
        const float4 w0 = W4[(size_t)(k + 0) * 32 + tx];
        const float4 w1 = W4[(size_t)(k + 1) * 32 + tx];
        const float4 w2 = W4[(size_t)(k + 2) * 32 + tx];
        const float4 w3 = W4[(size_t)(k + 3) * 32 + tx];
        #pragma unroll
        for (int i = 0; i < 4; ++i) {
            const float4 xv = xr[i][kk];
            acc[i].x = fmaf(xv.x, w0.x, acc[i].x);
            acc[i].y = fmaf(xv.x, w0.y, acc[i].y);
            acc[i].z = fmaf(xv.x, w0.z, acc[i].z);
            acc[i].w = fmaf(xv.x, w0.w, acc[i].w);
            acc[i].x = fmaf(xv.y, w1.x, acc[i].x);
            acc[i].y = fmaf(xv.y, w1.y, acc[i].y);
            acc[i].z = fmaf(xv.y, w1.z, acc[i].z);
            acc[i].w = fmaf(xv.y, w1.w, acc[i].w);
            acc[i].x = fmaf(xv.z, w2.x, acc[i].x);
            acc[i].y = fmaf(xv.z, w2.y, acc[i].y);
            acc[i].z = fmaf(xv.z, w2.z, acc[i].z);
            acc[i].w = fmaf(xv.z, w2.w, acc[i].w);
            acc[i].x = fmaf(xv.w, w3.x, acc[i].x);
            acc[i].y = fmaf(xv.w, w3.y, acc[i].y);
            acc[i].z = fmaf(xv.w, w3.z, acc[i].z);
            acc[i].w = fmaf(xv.w, w3.w, acc[i].w);
        }
    }
    #pragma unroll
    for (int i = 0; i < 4; ++i) {
        const int r = r0 + i;
        const float di = dinv[r];
        const size_t o = (size_t)r * HID + c;
        *reinterpret_cast<float4*>(h1 + o) = acc[i];
        float4 sv = make_float4(di * acc[i].x, di * acc[i].y,
                                di * acc[i].z, di * acc[i].w);
        st_h4(s0 + o, sv);
        float4 hv = make_float4(C_RES * sv.x, C_RES * sv.y,
                                C_RES * sv.z, C_RES * sv.w);
        *reinterpret_cast<float4*>(hb + o) = hv;
    }
}

// ---------------------------------------------------------------------------
// 3) layer-1 diffusion step in pre-scaled space (s = dinv (.) out, fp16):
//    s'_ic = A_i * ( sum_{j in nbr(i)} s_jc + s_ic ) + hb_ic
//    thread = 1 row x 4 cols; 32 lanes/row; 8 rows/block.
// ---------------------------------------------------------------------------
__global__ __launch_bounds__(256) void diffuse1_kernel(
    const __half* __restrict__ sin, const float* __restrict__ hb,
    __half* __restrict__ sout,
    const int* __restrict__ ell, const int* __restrict__ nnz,
    const float* __restrict__ arow)
{
    const int tx = threadIdx.x & 31;
    const int r  = blockIdx.x * 8 + (threadIdx.x >> 5);
    const int c  = tx * 4;
    const int nn = nnz[r];
    const int* __restrict__ erow = ell + (size_t)r * MAX_ELL;

    float4 a0 = ld_h4(sin + (size_t)r * HID + c);   // self term
    float4 a1 = {0.f, 0.f, 0.f, 0.f};
    int t = 0;
    for (; t + 2 <= nn; t += 2) {
        const int j0 = erow[t];
        const int j1 = erow[t + 1];
        const float4 g0 = ld_h4(sin + (size_t)j0 * HID + c);
        const float4 g1 = ld_h4(sin + (size_t)j1 * HID + c);
        add4(a0, g0);
        add4(a1, g1);
    }
    if (t < nn) add4(a0, ld_h4(sin + (size_t)erow[t] * HID + c));
    add4(a0, a1);

    const float Ai = arow[r];
    const float4 hv = *reinterpret_cast<const float4*>(hb + (size_t)r * HID + c);
    float4 s = make_float4(fmaf(Ai, a0.x, hv.x), fmaf(Ai, a0.y, hv.y),
                           fmaf(Ai, a0.z, hv.z), fmaf(Ai, a0.w, hv.w));
    st_h4(sout + (size_t)r * HID + c, s);
}

// ---------------------------------------------------------------------------
// 4) layer-1 final step: o1 = relu(cprop*dinv_i*G + cres*h1 + b1)  (fp32 out)
// ---------------------------------------------------------------------------
__global__ __launch_bounds__(256) void final1_kernel(
    const __half* __restrict__ sin, const float* __restrict__ h1,
    const float* __restrict__ b1, float* __restrict__ o1,
    const int* __restrict__ ell, const int* __restrict__ nnz,
    const float* __restrict__ dinv)
{
    const int tx = threadIdx.x & 31;
    const int r  = blockIdx.x * 8 + (threadIdx.x >> 5);
    const int c  = tx * 4;
    const int nn = nnz[r];
    const int* __restrict__ erow = ell + (size_t)r * MAX_ELL;

    float4 a0 = ld_h4(sin + (size_t)r * HID + c);
    float4 a1 = {0.f, 0.f, 0.f, 0.f};
    int t = 0;
    for (; t + 2 <= nn; t += 2) {
        const int j0 = erow[t];
        const int j1 = erow[t + 1];
        const float4 g0 = ld_h4(sin + (size_t)j0 * HID + c);
        const float4 g1 = ld_h4(sin + (size_t)j1 * HID + c);
        add4(a0, g0);
        add4(a1, g1);
    }
    if (t < nn) add4(a0, ld_h4(sin + (size_t)erow[t] * HID + c));
    add4(a0, a1);

    const float pd = C_PROP * dinv[r];
    const float4 hv = *reinterpret_cast<const float4*>(h1 + (size_t)r * HID + c);
    const float4 bv = *reinterpret_cast<const float4*>(b1 + c);
    float4 o;
    o.x = fmaxf(fmaf(pd, a0.x, C_RES * hv.x) + bv.x, 0.f);
    o.y = fmaxf(fmaf(pd, a0.y, C_RES * hv.y) + bv.y, 0.f);
    o.z = fmaxf(fmaf(pd, a0.z, C_RES * hv.z) + bv.z, 0.f);
    o.w = fmaxf(fmaf(pd, a0.w, C_RES * hv.w) + bv.w, 0.f);
    *reinterpret_cast<float4*>(o1 + (size_t)r * HID + c) = o;
}

// ---------------------------------------------------------------------------
// 5) h2 = o1 @ W2 (8192x128 @ 128x16); epilogue writes h2, s2_0 = dinv*h2,
//    hb2 = cres*dinv*h2 (all fp32 - layer 2 is tiny).
// ---------------------------------------------------------------------------
__global__ __launch_bounds__(256) void gemm_hw2_kernel(
    const float* __restrict__ o1, const float* __restrict__ W2,
    const float* __restrict__ dinv,
    float* __restrict__ h2, float* __restrict__ s2, float* __restrict__ hb2)
{
    const int c = threadIdx.x & (NCLS - 1);
    const int r = blockIdx.x * 16 + (threadIdx.x >> 4);
    const float* ir = o1 + (size_t)r * HID;
    float acc = 0.f;
    #pragma unroll 8
    for (int k = 0; k < HID; ++k)
        acc = fmaf(ir[k], W2[k * NCLS + c], acc);
    const float di = dinv[r];
    const size_t o = (size_t)r * NCLS + c;
    h2[o]  = acc;
    s2[o]  = di * acc;
    hb2[o] = C_RES * di * acc;
}

// ---------------------------------------------------------------------------
// 6) layer-2 diffusion step (fp32, 16 cols = 4 lanes x float4, 64 rows/block)
// ---------------------------------------------------------------------------
__global__ __launch_bounds__(256) void diffuse2_kernel(
    const float* __restrict__ sin, const float* __restrict__ hb2,
    float* __restrict__ sout,
    const int* __restrict__ ell, const int* __restrict__ nnz,
    const float* __restrict__ arow)
{
    const int l4 = threadIdx.x & 3;
    const int r  = blockIdx.x * 64 + (threadIdx.x >> 2);
    const int c  = l4 * 4;
    const int nn = nnz[r];
    const int* __restrict__ erow = ell + (size_t)r * MAX_ELL;

    float4 a0 = *reinterpret_cast<const float4*>(sin + (size_t)r * NCLS + c);
    float4 a1 = {0.f, 0.f, 0.f, 0.f};
    int t = 0;
    for (; t + 2 <= nn; t += 2) {
        const int j0 = erow[t];
        const int j1 = erow[t + 1];
        const float4 g0 = *reinterpret_cast<const float4*>(sin + (size_t)j0 * NCLS + c);
        const float4 g1 = *reinterpret_cast<const float4*>(sin + (size_t)j1 * NCLS + c);
        add4(a0, g0);
        add4(a1, g1);
    }
    if (t < nn) add4(a0, *reinterpret_cast<const float4*>(sin + (size_t)erow[t] * NCLS + c));
    add4(a0, a1);

    const float Ai = arow[r];
    const float4 hv = *reinterpret_cast<const float4*>(hb2 + (size_t)r * NCLS + c);
    float4 s = make_float4(fmaf(Ai, a0.x, hv.x), fmaf(Ai, a0.y, hv.y),
                           fmaf(Ai, a0.z, hv.z), fmaf(Ai, a0.w, hv.w));
    *reinterpret_cast<float4*>(sout + (size_t)r * NCLS + c) = s;
}

// ---------------------------------------------------------------------------
// 7) layer-2 final step fused with log_softmax:
//    o = cprop*dinv_i*G + cres*h2 + b2; out = o - logsumexp(o) over 16 cols
//    (row = aligned lane quad -> __shfl_xor 1,2).
// ---------------------------------------------------------------------------
__global__ __launch_bounds__(256) void final2_lsm_kernel(
    const float* __restrict__ sin, const float* __restrict__ h2,
    const float* __restrict__ b2, float* __restrict__ out,
    const int* __restrict__ ell, const int* __restrict__ nnz,
    const float* __restrict__ dinv)
{
    const int l4 = threadIdx.x & 3;
    const int r  = blockIdx.x * 64 + (threadIdx.x >> 2);
    const int c  = l4 * 4;
    const int nn = nnz[r];
    const int* __restrict__ erow = ell + (size_t)r * MAX_ELL;

    float4 a0 = *reinterpret_cast<const float4*>(sin + (size_t)r * NCLS + c);
    float4 a1 = {0.f, 0.f, 0.f, 0.f};
    int t = 0;
    for (; t + 2 <= nn; t += 2) {
        const int j0 = erow[t];
        const int j1 = erow[t + 1];
        const float4 g0 = *reinterpret_cast<const float4*>(sin + (size_t)j0 * NCLS + c);
        const float4 g1 = *reinterpret_cast<const float4*>(sin + (size_t)j1 * NCLS + c);
        add4(a0, g0);
        add4(a1, g1);
    }
    if (t < nn) add4(a0, *reinterpret_cast<const float4*>(sin + (size_t)erow[t] * NCLS + c));
    add4(a0, a1);

    const float pd = C_PROP * dinv[r];
    const float4 hv = *reinterpret_cast<const float4*>(h2 + (size_t)r * NCLS + c);
    const float4 bv = *reinterpret_cast<const float4*>(b2 + c);
    float4 o;
    o.x = fmaf(pd, a0.x, C_RES * hv.x) + bv.x;
    o.y = fmaf(pd, a0.y, C_RES * hv.y) + bv.y;
    o.z = fmaf(pd, a0.z, C_RES * hv.z) + bv.z;
    o.w = fmaf(pd, a0.w, C_RES * hv.w) + bv.w;

    float mx = fmaxf(fmaxf(o.x, o.y), fmaxf(o.z, o.w));
    mx = fmaxf(mx, __shfl_xor(mx, 1));
    mx = fmaxf(mx, __shfl_xor(mx, 2));
    float s = __expf(o.x - mx) + __expf(o.y - mx) + __expf(o.z - mx) + __expf(o.w - mx);
    s += __shfl_xor(s, 1);
    s += __shfl_xor(s, 2);
    const float lse = mx + __logf(s);
    float4 res = make_float4(o.x - lse, o.y - lse, o.z - lse, o.w - lse);
    *reinterpret_cast<float4*>(out + (size_t)r * NCLS + c) = res;
}

// ---------------------------------------------------------------------------
extern "C" void kernel_launch(void* const* d_in, const int* in_sizes, int n_in,
                              void* d_out, int out_size, void* d_ws, size_t ws_size,
                              hipStream_t stream)
{
    const float* x   = (const float*)d_in[0];
    const float* adj = (const float*)d_in[1];
    const float* W1  = (const float*)d_in[2];
    const float* b1  = (const float*)d_in[3];
    const float* W2  = (const float*)d_in[4];
    const float* b2  = (const float*)d_in[5];
    float* out = (float*)d_out;

    char* ws = (char*)d_ws;
    size_t off = 0;
    auto carve = [&](size_t bytes) -> void* {
        void* p = ws + off;
        off += (bytes + 255) & ~(size_t)255;
        return p;
    };
    int*    ell  = (int*)   carve((size_t)N_NODES * MAX_ELL * sizeof(int));  // 8 MB
    int*    nnz  = (int*)   carve((size_t)N_NODES * sizeof(int));
    float*  dinv = (float*) carve((size_t)N_NODES * sizeof(float));
    float*  arow = (float*) carve((size_t)N_NODES * sizeof(float));
    float*  h1   = (float*) carve((size_t)N_NODES * HID * sizeof(float));    // 4 MB
    float*  hb   = (float*) carve((size_t)N_NODES * HID * sizeof(float));    // 4 MB
    __half* sA   = (__half*)carve((size_t)N_NODES * HID * sizeof(__half));   // 2 MB
    __half* sB   = (__half*)carve((size_t)N_NODES * HID * sizeof(__half));   // 2 MB
    float*  o1   = (float*) carve((size_t)N_NODES * HID * sizeof(float));    // 4 MB
    float*  h2   = (float*) carve((size_t)N_NODES * NCLS * sizeof(float));
    float*  hb2  = (float*) carve((size_t)N_NODES * NCLS * sizeof(float));
    float*  s2A  = (float*) carve((size_t)N_NODES * NCLS * sizeof(float));
    float*  s2B  = (float*) carve((size_t)N_NODES * NCLS * sizeof(float));

    // 1) adjacency scan (HBM floor ~45us)
    build_ell_kernel<<<N_NODES, 256, 0, stream>>>(adj, ell, nnz, dinv, arow);

    // 2) h1 = x@W1 (+ s0, hb epilogue)
    gemm_xw1_kernel<<<N_NODES / 32, 256, 0, stream>>>(x, W1, dinv, h1, sA, hb);

    // 3) layer-1: 7 s-space steps (fp16), then final step with +b1/relu
    {
        const __half* cur = sA;
        __half* bufs[2] = {sB, sA};
        for (int s = 0; s < 7; ++s) {
            __half* dst = bufs[s & 1];
            diffuse1_kernel<<<N_NODES / 8, 256, 0, stream>>>(cur, hb, dst, ell, nnz, arow);
            cur = dst;
        }
        final1_kernel<<<N_NODES / 8, 256, 0, stream>>>(cur, h1, b1, o1, ell, nnz, dinv);
    }

    // 4) h2 = o1@W2 (+ s2_0, hb2 epilogue)
    gemm_hw2_kernel<<<N_NODES / 16, 256, 0, stream>>>(o1, W2, dinv, h2, s2A, hb2);

    // 5) layer-2: 7 s-space steps (fp32), then final step fused with lsm
    {
        const float* cur = s2A;
        float* bufs[2] = {s2B, s2A};
        for (int s = 0; s < 7; ++s) {
            float* dst = bufs[s & 1];
            diffuse2_kernel<<<N_NODES / 64, 256, 0, stream>>>(cur, hb2, dst, ell, nnz, arow);
            cur = dst;
        }
        final2_lsm_kernel<<<N_NODES / 64, 256, 0, stream>>>(cur, h2, b2, out, ell, nnz, dinv);
    }
    (void)in_sizes; (void)n_in; (void)out_size; (void)ws_size;
}